// Round 1
// baseline (1063.730 us; speedup 1.0000x reference)
//
#include <hip/hip_runtime.h>

#define KN   32
#define DIN  128
#define DOUT 128
#define ROWS 132   // padded LDS row stride (floats); 132*4B keeps 16B alignment

// ---------------------------------------------------------------------------
// Kernel 1: fold W2@W4 -> u[128], W1@W4 -> v[128] into workspace.
// ---------------------------------------------------------------------------
__global__ void precompute_uv(const float* __restrict__ W1,
                              const float* __restrict__ W2,
                              const float* __restrict__ W4,
                              float* __restrict__ uv) {
    int tid = threadIdx.x;
    if (tid < DIN) {
        const float* row = W2 + tid * DOUT;
        float acc = 0.f;
        for (int e = 0; e < DOUT; ++e) acc += row[e] * W4[e];
        uv[tid] = acc;                       // u[d] = sum_e W2[d,e]*W4[e]
    } else if (tid < 2 * DIN) {
        int d = tid - DIN;
        const float* row = W1 + d * DOUT;
        float acc = 0.f;
        for (int e = 0; e < DOUT; ++e) acc += row[e] * W4[e];
        uv[DIN + d] = acc;                   // v[d] = sum_e W1[d,e]*W4[e]
    }
}

// ---------------------------------------------------------------------------
// Kernel 2: one block per n.
//   score_pre[k] = relu(self[n].v + neigh[n,k].u + sum_e sig(dt*W3[e])*W4[e] + b4)
//   score = softmax_k(score_pre); out[n,:] = sum_k score[k]*neigh[n,k,:]
// ---------------------------------------------------------------------------
__global__ __launch_bounds__(256) void attn_agg(
    const float* __restrict__ self_vecs,   // [N,128]
    const float* __restrict__ neigh_vecs,  // [N,32,128]
    const float* __restrict__ dt,          // [N,32]
    const float* __restrict__ W3,          // [128]
    const float* __restrict__ W4,          // [128]
    const float* __restrict__ b4,          // [1]
    const float* __restrict__ uv,          // u[128] ++ v[128]
    float* __restrict__ out,               // [N,128]
    float* __restrict__ score_out)         // [N,32]
{
    __shared__ __align__(16) float s_neigh[KN * ROWS];   // ~16.5 KB
    __shared__ float s_u[DIN];
    __shared__ float s_w3[DIN];
    __shared__ float s_w4[DIN];
    __shared__ float s_dt[KN];
    __shared__ float s_score[KN];
    __shared__ float s_qw4;

    const int n   = blockIdx.x;
    const int tid = threadIdx.x;

    // ---- stage params ----
    if (tid < DIN) {
        s_u[tid]  = uv[tid];
        s_w3[tid] = W3[tid];
        s_w4[tid] = W4[tid];
    }
    if (tid < KN) s_dt[tid] = dt[(size_t)n * KN + tid];

    // ---- stage neigh tile: 1024 float4 chunks, remapped to stride-132 rows ----
    const float4* gsrc = (const float4*)(neigh_vecs + (size_t)n * KN * DIN);
    #pragma unroll
    for (int i = 0; i < 4; ++i) {
        int c  = tid + 256 * i;     // 0..1023
        int kk = c >> 5;            // row (32 float4 per row)
        int qq = c & 31;            // quad within row
        float4 val = gsrc[c];
        *(float4*)(s_neigh + kk * ROWS + qq * 4) = val;
    }

    // ---- qW4 = self[n] . v  (wave 0) ----
    if (tid < 64) {
        const float* v = uv + DIN;
        const float* sv = self_vecs + (size_t)n * DIN;
        float p = sv[tid] * v[tid] + sv[tid + 64] * v[tid + 64];
        #pragma unroll
        for (int off = 32; off > 0; off >>= 1)
            p += __shfl_down(p, off, 64);
        if (tid == 0) s_qw4 = p;
    }
    __syncthreads();

    // ---- scores: 8 threads per k ----
    {
        const int k   = tid >> 3;   // 0..31
        const int sub = tid & 7;    // 0..7
        const float* row = s_neigh + k * ROWS;
        const float dtk  = s_dt[k];
        float dotp = 0.f, tt = 0.f;
        #pragma unroll
        for (int j = 0; j < 16; ++j) {
            int e = sub + 8 * j;                    // stride-8 interleave
            dotp += row[e] * s_u[e];
            float sg = 1.0f / (1.0f + __expf(-dtk * s_w3[e]));
            tt += sg * s_w4[e];
        }
        float p = dotp + tt;
        p += __shfl_down(p, 4, 8);
        p += __shfl_down(p, 2, 8);
        p += __shfl_down(p, 1, 8);
        if (sub == 0) {
            float sp = s_qw4 + p + b4[0];
            s_score[k] = sp > 0.f ? sp : 0.f;
        }
    }
    __syncthreads();

    // ---- softmax over k (lanes 0..31 of wave 0) ----
    if (tid < KN) {
        float x  = s_score[tid];
        float mx = x;
        #pragma unroll
        for (int off = 16; off > 0; off >>= 1)
            mx = fmaxf(mx, __shfl_xor(mx, off, 32));
        float ex = __expf(x - mx);
        float sm = ex;
        #pragma unroll
        for (int off = 16; off > 0; off >>= 1)
            sm += __shfl_xor(sm, off, 32);
        float sc = ex / sm;
        s_score[tid] = sc;
        score_out[(size_t)n * KN + tid] = sc;
    }
    __syncthreads();

    // ---- weighted neighbor sum: thread e in [0,128) ----
    if (tid < DIN) {
        float acc = 0.f;
        #pragma unroll
        for (int kk = 0; kk < KN; ++kk)
            acc += s_score[kk] * s_neigh[kk * ROWS + tid];
        out[(size_t)n * DIN + tid] = acc;
    }
}

// ---------------------------------------------------------------------------
extern "C" void kernel_launch(void* const* d_in, const int* in_sizes, int n_in,
                              void* d_out, int out_size, void* d_ws, size_t ws_size,
                              hipStream_t stream) {
    const float* self_vecs = (const float*)d_in[0];
    const float* neigh     = (const float*)d_in[1];
    const float* dtim      = (const float*)d_in[2];
    const float* W1        = (const float*)d_in[3];
    const float* W2        = (const float*)d_in[4];
    const float* W3        = (const float*)d_in[5];
    const float* W4        = (const float*)d_in[6];
    const float* b4        = (const float*)d_in[7];

    const int N = in_sizes[0] / DIN;           // 50000
    float* uv        = (float*)d_ws;           // 256 floats
    float* out       = (float*)d_out;          // [N,128]
    float* score_out = out + (size_t)N * DIN;  // [N,32]

    precompute_uv<<<1, 256, 0, stream>>>(W1, W2, W4, uv);
    attn_agg<<<N, 256, 0, stream>>>(self_vecs, neigh, dtim, W3, W4, b4,
                                    uv, out, score_out);
}